// Round 1
// baseline (143.477 us; speedup 1.0000x reference)
//
#include <hip/hip_runtime.h>
#include <math.h>

// Contour-to-distance-map: for each pixel p=(i/S, j/S), over N contour points:
//   diff_n = c_n - p ; next = c_{n+1 mod N} - p
//   sign = tanh(k*(diff.y*next.x - diff.x*next.y)),  k = 1e5
//   ang  = acos(clip(dot(diff,next)/(max(|diff|,eps)*max(|next|,eps)), -1+eps, 1-eps))
//   winding = sum(sign*ang)/(2*pi) ; min_diff = min_n |diff_n|
//   prod = winding*min_diff ; out = prod / max(prod)
// Pass 1: prod -> d_out, global max -> d_ws[0] (int-trick atomic).
// Pass 2: in-place divide.

#define EPS  1e-5f
#define KK   100000.0f
#define INV_2PI 0.15915494309189535f

__device__ __forceinline__ void atomic_max_float(float* addr, float val) {
    // Standard mixed int/uint trick; addr pre-initialized to 0xFFFFFFFF bytes
    // (int -1 / uint max), so either path makes progress.
    if (!(val < 0.0f)) {
        atomicMax((int*)addr, __float_as_int(val));
    } else {
        atomicMin((unsigned int*)addr, __float_as_uint(val));
    }
}

__global__ void __launch_bounds__(256)
winding_kernel(const float2* __restrict__ contour, int N, int S, float invS,
               float* __restrict__ out, float* __restrict__ gmax) {
    __shared__ float2 sc[256];           // N <= 256 (actual 200): 2 KB LDS
    const int tid = threadIdx.x;
    for (int t = tid; t < N; t += blockDim.x) sc[t] = contour[t];
    __syncthreads();

    const int p = blockIdx.x * blockDim.x + tid;
    const int total = S * S;
    float prod = -INFINITY;              // identity for the max-reduction

    if (p < total) {
        const int i = p / S;
        const int j = p - i * S;
        const float px = (float)i * invS;
        const float py = (float)j * invS;

        // carry current-vertex diff; each vertex's diff/norm computed once
        float dxc = sc[0].x - px;
        float dyc = sc[0].y - py;
        float normc = sqrtf(fmaf(dxc, dxc, dyc * dyc));
        float minn = normc;
        float w = 0.0f;

        for (int n = 0; n < N; ++n) {
            const int nn = (n + 1 == N) ? 0 : n + 1;
            const float2 cn = sc[nn];
            const float dxn = cn.x - px;
            const float dyn = cn.y - py;
            const float normn = sqrtf(fmaf(dxn, dxn, dyn * dyn));
            minn = fminf(minn, normn);

            // cross term per reference: diff.y*next.x - diff.x*next.y
            const float cross = dyc * dxn - dxc * dyn;
            const float dot   = fmaf(dxc, dxn, dyc * dyn);
            const float denom = fmaxf(normc, EPS) * fmaxf(normn, EPS);
            float cosang = dot / denom;
            cosang = fminf(fmaxf(cosang, -1.0f + EPS), 1.0f - EPS);
            const float ang = acosf(cosang);

            // tanh(KK*cross) = copysign((1-e)/(1+e), cross), e = exp(-2*KK*|cross|)
            const float a = fabsf(cross) * (2.0f * KK);
            const float e = __expf(-a);
            float t = (1.0f - e) / (1.0f + e);
            t = copysignf(t, cross);

            w = fmaf(t, ang, w);
            dxc = dxn; dyc = dyn; normc = normn;
        }

        prod = (w * INV_2PI) * minn;
        out[p] = prod;
    }

    // block max -> one atomic per block
    float v = prod;
    #pragma unroll
    for (int off = 32; off >= 1; off >>= 1)
        v = fmaxf(v, __shfl_down(v, off, 64));
    __shared__ float wmax[4];
    const int lane = tid & 63;
    const int wid  = tid >> 6;
    if (lane == 0) wmax[wid] = v;
    __syncthreads();
    if (tid == 0) {
        float m = fmaxf(fmaxf(wmax[0], wmax[1]), fmaxf(wmax[2], wmax[3]));
        atomic_max_float(gmax, m);
    }
}

__global__ void __launch_bounds__(256)
normalize_kernel(float* __restrict__ out, const float* __restrict__ gmax, int total) {
    const int p = blockIdx.x * blockDim.x + threadIdx.x;
    const float m = *gmax;
    if (p < total) out[p] = out[p] / m;
}

extern "C" void kernel_launch(void* const* d_in, const int* in_sizes, int n_in,
                              void* d_out, int out_size, void* d_ws, size_t ws_size,
                              hipStream_t stream) {
    const float2* contour = (const float2*)d_in[0];
    const int N = in_sizes[0] / 2;                       // 200
    const int S = (int)(sqrt((double)out_size) + 0.5);   // 384
    const float invS = 1.0f / (float)S;
    float* out  = (float*)d_out;
    float* gmax = (float*)d_ws;

    // init the atomic-max slot: 0xFFFFFFFF works for the int/uint trick
    hipMemsetAsync(gmax, 0xFF, sizeof(float), stream);

    const int total = S * S;
    const int blocks = (total + 255) / 256;
    winding_kernel<<<blocks, 256, 0, stream>>>(contour, N, S, invS, out, gmax);
    normalize_kernel<<<blocks, 256, 0, stream>>>(out, gmax, total);
}

// Round 2
// 96.833 us; speedup vs baseline: 1.4817x; 1.4817x over previous
//
#include <hip/hip_runtime.h>
#include <math.h>

// Contour-to-distance-map, round 2.
// R1 evidence: winding_kernel 100.8us, VALUBusy 62%, Occupancy 14% (576 blocks
// = 2.25 waves/SIMD), VGPR=16, HBM ~0 -> latency-bound on the per-iteration
// dependent chain (IEEE div + libm acosf + IEEE div ~ 533 cy/iter observed).
// Changes:
//   (a) 4-way vertex-loop split: block = 4 waves, each wave does 50 of the
//       200 vertices for the same 64 pixels; LDS combine. Grid 576 -> 2304
//       blocks -> occupancy saturates (9 waves/SIMD demanded vs 8 cap).
//   (b) chain shortening: v_rcp_f32 instead of IEEE div (2x), polynomial
//       acos (A&S 4.4.46, |err|<2e-8) instead of libm acosf.
//   (c) no-atomic max: per-block max -> d_ws[block]; normalize kernel
//       reduces the 2304 block maxes (L2-hit) and scales with float4.
//       Removes the hipMemsetAsync launch.

#define EPS  1e-5f
#define KK   100000.0f
#define INV_2PI 0.15915494309189535f
#define PI_F 3.14159265358979323846f

__device__ __forceinline__ float acos_poly(float x) {
    // acos(x) = sqrt(1-|x|)*p(|x|), reflect for x<0. A&S 4.4.46, |err|<2e-8.
    const float u = fabsf(x);
    float p = fmaf(u, -0.0012624911f, 0.0066700901f);
    p = fmaf(u, p, -0.0170881256f);
    p = fmaf(u, p,  0.0308918810f);
    p = fmaf(u, p, -0.0501743046f);
    p = fmaf(u, p,  0.0889789874f);
    p = fmaf(u, p, -0.2145988016f);
    p = fmaf(u, p,  1.5707963050f);
    const float r = __builtin_amdgcn_sqrtf(1.0f - u) * p;
    return (x >= 0.0f) ? r : PI_F - r;
}

__global__ void __launch_bounds__(256)
winding_kernel(const float2* __restrict__ contour, int N, int S, float invS,
               float* __restrict__ out, float* __restrict__ bmax) {
    __shared__ float2 sc[256];         // N <= 256 (actual 200)
    __shared__ float s_w[4][64];
    __shared__ float s_min[4][64];

    const int tid  = threadIdx.x;
    const int lane = tid & 63;
    const int wid  = tid >> 6;

    for (int t = tid; t < N; t += blockDim.x) sc[t] = contour[t];
    __syncthreads();

    const int p = blockIdx.x * 64 + lane;      // 64 pixels per block
    const int total = S * S;
    const bool valid = (p < total);

    const int i = p / S;
    const int j = p - i * S;
    const float px = (float)i * invS;
    const float py = (float)j * invS;

    // this wave's vertex range [n0, n1)
    const int Q  = (N + 3) >> 2;
    const int n0 = wid * Q;
    const int n1 = (n0 + Q < N) ? (n0 + Q) : N;

    float w = 0.0f;
    float minn = INFINITY;

    if (valid && n0 < n1) {
        float dxc = sc[n0].x - px;
        float dyc = sc[n0].y - py;
        float normc = __builtin_amdgcn_sqrtf(fmaf(dxc, dxc, dyc * dyc));
        minn = normc;

        for (int n = n0; n < n1; ++n) {
            const int nn = (n + 1 == N) ? 0 : n + 1;
            const float2 cn = sc[nn];
            const float dxn = cn.x - px;
            const float dyn = cn.y - py;
            const float normn = __builtin_amdgcn_sqrtf(fmaf(dxn, dxn, dyn * dyn));
            minn = fminf(minn, normn);

            const float cross = dyc * dxn - dxc * dyn;   // per reference
            const float dot   = fmaf(dxc, dxn, dyc * dyn);
            const float denom = fmaxf(normc, EPS) * fmaxf(normn, EPS);
            float cosang = dot * __builtin_amdgcn_rcpf(denom);
            cosang = fminf(fmaxf(cosang, -1.0f + EPS), 1.0f - EPS);
            const float ang = acos_poly(cosang);

            // tanh(KK*cross) = copysign((1-e)/(1+e), cross), e = exp(-2KK|cross|)
            const float a = fabsf(cross) * (2.0f * KK);
            const float e = __expf(-a);
            float t = (1.0f - e) * __builtin_amdgcn_rcpf(1.0f + e);
            t = copysignf(t, cross);

            w = fmaf(t, ang, w);
            dxc = dxn; dyc = dyn; normc = normn;
        }
    }

    s_w[wid][lane]   = w;
    s_min[wid][lane] = minn;
    __syncthreads();

    if (wid == 0) {
        const float wt = ((s_w[0][lane] + s_w[1][lane]) +
                          (s_w[2][lane] + s_w[3][lane]));
        const float mt = fminf(fminf(s_min[0][lane], s_min[1][lane]),
                               fminf(s_min[2][lane], s_min[3][lane]));
        float prod = valid ? (wt * INV_2PI) * mt : -INFINITY;
        if (valid) out[p] = prod;

        float v = prod;
        #pragma unroll
        for (int off = 32; off >= 1; off >>= 1)
            v = fmaxf(v, __shfl_down(v, off, 64));
        if (lane == 0) bmax[blockIdx.x] = v;
    }
}

__global__ void __launch_bounds__(256)
normalize_kernel(float4* __restrict__ out4, const float* __restrict__ bmax,
                 int nblocks, int total4) {
    const int tid  = threadIdx.x;
    const int lane = tid & 63;
    const int wid  = tid >> 6;

    // every block reduces all block-maxes (L2-resident, ~2304 floats)
    float m = -INFINITY;
    for (int t = tid; t < nblocks; t += 256) m = fmaxf(m, bmax[t]);
    #pragma unroll
    for (int off = 32; off >= 1; off >>= 1)
        m = fmaxf(m, __shfl_down(m, off, 64));
    __shared__ float sm[4];
    if (lane == 0) sm[wid] = m;
    __syncthreads();
    m = fmaxf(fmaxf(sm[0], sm[1]), fmaxf(sm[2], sm[3]));
    const float inv = 1.0f / m;

    const int idx = blockIdx.x * 256 + tid;
    if (idx < total4) {
        float4 v = out4[idx];
        v.x *= inv; v.y *= inv; v.z *= inv; v.w *= inv;
        out4[idx] = v;
    }
}

extern "C" void kernel_launch(void* const* d_in, const int* in_sizes, int n_in,
                              void* d_out, int out_size, void* d_ws, size_t ws_size,
                              hipStream_t stream) {
    const float2* contour = (const float2*)d_in[0];
    const int N = in_sizes[0] / 2;                       // 200
    const int S = (int)(sqrt((double)out_size) + 0.5);   // 384
    const float invS = 1.0f / (float)S;
    float* out  = (float*)d_out;
    float* bmax = (float*)d_ws;

    const int total = S * S;
    const int wblocks = (total + 63) / 64;               // 2304
    winding_kernel<<<wblocks, 256, 0, stream>>>(contour, N, S, invS, out, bmax);

    const int total4  = total / 4;                       // S^2 divisible by 4
    const int nblocks = (total4 + 255) / 256;            // 144
    normalize_kernel<<<nblocks, 256, 0, stream>>>((float4*)out, bmax, wblocks, total4);
}

// Round 3
// 87.365 us; speedup vs baseline: 1.6423x; 1.1084x over previous
//
#include <hip/hip_runtime.h>
#include <math.h>

// Contour-to-distance-map, round 3.
// R2 evidence: winding 44.2us vs ~17us issue floor (92 cy/iter x 2304
// pixel-waves x 200 iters / 1024 SIMDs). VGPR=12, 9 waves/SIMD demanded vs 8
// cap -> latency-bound with a tail. Fix: 2 independent pixel chains per lane
// (ILP-2), grid 2304->1152 blocks (4.5 waves/SIMD demanded, chains hide the
// rest). Plus: sc[N]=sc[0] sentinel (no wrap select), min over squared dist
// (one epilogue sqrt), rsq(d2c*d2n) instead of sqrt+rcp in the chain.

#define EPS   1e-5f
#define EPS2  1e-10f
#define KK    100000.0f
#define INV_2PI 0.15915494309189535f
#define PI_F 3.14159265358979323846f

__device__ __forceinline__ float acos_poly(float x) {
    // acos(x) = sqrt(1-|x|)*p(|x|), reflect for x<0. A&S 4.4.46, |err|<2e-8.
    const float u = fabsf(x);
    float p = fmaf(u, -0.0012624911f, 0.0066700901f);
    p = fmaf(u, p, -0.0170881256f);
    p = fmaf(u, p,  0.0308918810f);
    p = fmaf(u, p, -0.0501743046f);
    p = fmaf(u, p,  0.0889789874f);
    p = fmaf(u, p, -0.2145988016f);
    p = fmaf(u, p,  1.5707963050f);
    const float r = __builtin_amdgcn_sqrtf(1.0f - u) * p;
    return (x >= 0.0f) ? r : PI_F - r;
}

struct Chain {
    float dxc, dyc, d2cm, minn, w;
};

__device__ __forceinline__ void chain_init(Chain& c, float c0x, float c0y,
                                           float px, float py) {
    c.dxc = c0x - px;
    c.dyc = c0y - py;
    const float d2 = fmaf(c.dxc, c.dxc, c.dyc * c.dyc);
    c.minn = d2;
    c.d2cm = fmaxf(d2, EPS2);
    c.w = 0.0f;
}

__device__ __forceinline__ void chain_step(Chain& c, float cnx, float cny,
                                           float px, float py) {
    const float dxn = cnx - px;
    const float dyn = cny - py;
    const float d2n = fmaf(dxn, dxn, dyn * dyn);
    c.minn = fminf(c.minn, d2n);
    const float d2nm = fmaxf(d2n, EPS2);
    const float rs = __builtin_amdgcn_rsqf(c.d2cm * d2nm);

    const float dot   = fmaf(c.dxc, dxn, c.dyc * dyn);
    const float cross = fmaf(-c.dxc, dyn, c.dyc * dxn);  // dyc*dxn - dxc*dyn

    float cosang = dot * rs;
    cosang = fminf(fmaxf(cosang, -1.0f + EPS), 1.0f - EPS);
    const float ang = acos_poly(cosang);

    // tanh(KK*|cross|) = (1-e)/(1+e), e = exp(-2*KK*|cross|)
    const float a = fabsf(cross) * (2.0f * KK);
    const float e = __expf(-a);
    float t = (1.0f - e) * __builtin_amdgcn_rcpf(1.0f + e);
    t = copysignf(t, cross);

    c.w = fmaf(t, ang, c.w);
    c.dxc = dxn; c.dyc = dyn; c.d2cm = d2nm;
}

__global__ void __launch_bounds__(256)
winding_kernel(const float2* __restrict__ contour, int N, int S, float invS,
               float* __restrict__ out, float* __restrict__ bmax) {
    __shared__ float2 sc[257];           // N+1 <= 257, sc[N] = sc[0] sentinel
    __shared__ float s_w[4][128];
    __shared__ float s_m[4][128];

    const int tid  = threadIdx.x;
    const int lane = tid & 63;
    const int wid  = tid >> 6;

    for (int t = tid; t < N; t += 256) sc[t] = contour[t];
    if (tid == 0) sc[N] = contour[0];
    __syncthreads();

    const int total = S * S;
    const int p0 = blockIdx.x * 128 + lane;   // 128 pixels/block, 2 per lane
    const int p1 = p0 + 64;
    const bool v0 = (p0 < total);
    const bool v1 = (p1 < total);

    const int i0 = p0 / S, j0 = p0 - i0 * S;
    const int i1 = p1 / S, j1 = p1 - i1 * S;
    const float px0 = (float)i0 * invS, py0 = (float)j0 * invS;
    const float px1 = (float)i1 * invS, py1 = (float)j1 * invS;

    // this wave's vertex range [n0, n1)
    const int Q  = (N + 3) >> 2;
    const int n0 = wid * Q;
    const int n1 = (n0 + Q < N) ? (n0 + Q) : N;

    Chain c0, c1;
    chain_init(c0, sc[n0].x, sc[n0].y, px0, py0);
    chain_init(c1, sc[n0].x, sc[n0].y, px1, py1);

    #pragma unroll 4
    for (int n = n0; n < n1; ++n) {
        const float2 cn = sc[n + 1];          // sentinel handles wrap
        chain_step(c0, cn.x, cn.y, px0, py0);
        chain_step(c1, cn.x, cn.y, px1, py1);
    }

    s_w[wid][lane]      = c0.w;
    s_w[wid][lane + 64] = c1.w;
    s_m[wid][lane]      = c0.minn;
    s_m[wid][lane + 64] = c1.minn;
    __syncthreads();

    if (wid < 2) {
        const int idx = wid * 64 + lane;      // entry -> pixel blockIdx*128+idx
        const int pix = blockIdx.x * 128 + idx;
        const bool valid = (wid == 0) ? v0 : v1;

        const float wt = (s_w[0][idx] + s_w[1][idx]) +
                         (s_w[2][idx] + s_w[3][idx]);
        const float mt = fminf(fminf(s_m[0][idx], s_m[1][idx]),
                               fminf(s_m[2][idx], s_m[3][idx]));
        float prod = valid ? (wt * INV_2PI) * __builtin_amdgcn_sqrtf(mt)
                           : -INFINITY;
        if (valid) out[pix] = prod;

        float v = prod;
        #pragma unroll
        for (int off = 32; off >= 1; off >>= 1)
            v = fmaxf(v, __shfl_down(v, off, 64));
        if (lane == 0) bmax[blockIdx.x * 2 + wid] = v;
    }
}

__global__ void __launch_bounds__(256)
normalize_kernel(float4* __restrict__ out4, const float* __restrict__ bmax,
                 int nmax, int total4) {
    const int tid  = threadIdx.x;
    const int lane = tid & 63;
    const int wid  = tid >> 6;

    float m = -INFINITY;
    for (int t = tid; t < nmax; t += 256) m = fmaxf(m, bmax[t]);
    #pragma unroll
    for (int off = 32; off >= 1; off >>= 1)
        m = fmaxf(m, __shfl_down(m, off, 64));
    __shared__ float sm[4];
    if (lane == 0) sm[wid] = m;
    __syncthreads();
    m = fmaxf(fmaxf(sm[0], sm[1]), fmaxf(sm[2], sm[3]));
    const float inv = 1.0f / m;

    const int idx = blockIdx.x * 256 + tid;
    if (idx < total4) {
        float4 v = out4[idx];
        v.x *= inv; v.y *= inv; v.z *= inv; v.w *= inv;
        out4[idx] = v;
    }
}

extern "C" void kernel_launch(void* const* d_in, const int* in_sizes, int n_in,
                              void* d_out, int out_size, void* d_ws, size_t ws_size,
                              hipStream_t stream) {
    const float2* contour = (const float2*)d_in[0];
    const int N = in_sizes[0] / 2;                       // 200
    const int S = (int)(sqrt((double)out_size) + 0.5);   // 384
    const float invS = 1.0f / (float)S;
    float* out  = (float*)d_out;
    float* bmax = (float*)d_ws;

    const int total   = S * S;
    const int wblocks = (total + 127) / 128;             // 1152
    winding_kernel<<<wblocks, 256, 0, stream>>>(contour, N, S, invS, out, bmax);

    const int total4  = total / 4;
    const int nblocks = (total4 + 255) / 256;            // 144
    normalize_kernel<<<nblocks, 256, 0, stream>>>((float4*)out, bmax,
                                                  wblocks * 2, total4);
}